// Round 8
// baseline (140.536 us; speedup 1.0000x reference)
//
#include <hip/hip_runtime.h>

#define P 10
#define D 1024
#define NROWS 16384
#define R 3                        // rows per thread (state 96 floats, target <=128 VGPR)

typedef float nfloat4 __attribute__((ext_vector_type(4)));   // clang-native for nontemporal builtins

// ---------------------------------------------------------------------------
// Column mapping (unchanged from round 4):
//   k = e_hi*256 + lane*4 + e_lo,  e = e_hi*4 + e_lo,  e in [0,16), lane in [0,64)
//   stage j flips bit j of k:
//     j=0,1  -> e_lo bits -> intra-thread (partner e^1 / e^2)
//     j=2..7 -> lane bits -> __shfl_xor mask 1<<(j-2)
//     j=8,9  -> e_hi bits -> intra-thread (partner e^4 / e^8)
// Coef table swizzled: coef[j*D + e*64 + lane] = (u_re,u_im,v_re,v_im) for k(e,lane).
// psi folded into stage-9 coefs. Each coef load feeds R=3 rows.
// Row guards are wave-uniform (row validity depends on wave only), so the
// tail block branches via s_cbranch, no lane divergence.
// ---------------------------------------------------------------------------
__global__ void coef_kernel(const float* __restrict__ theta,
                            const float* __restrict__ phi,
                            const float* __restrict__ psi,
                            float4* __restrict__ coef) {
    int idx = blockIdx.x * blockDim.x + threadIdx.x;
    if (idx >= P * D) return;
    int j = idx >> 10;
    int slot = idx & (D - 1);
    int e = slot >> 6;
    int lane = slot & 63;
    int k = ((e >> 2) << 8) + (lane << 2) + (e & 3);   // column this slot serves
    int b = (k >> j) & 1;
    unsigned lowmask = (1u << j) - 1u;
    unsigned m = ((unsigned)k & lowmask) | (((unsigned)k >> 1) & ~lowmask); // delete bit j
    float th = theta[j * (D / 2) + m];
    float ph = phi[j * (D / 2) + m];
    float h = th * 0.5f;
    float s1 = sinf(h), c1 = cosf(h);
    float s2 = sinf(h + ph), c2 = cosf(h + ph);
    float ur, ui, vr, vi;
    if (b) { ur =  s1 * s1; vr = -c1 * s2; ui = -c1 * s1; vi = c1 * c2; }
    else   { ur = -s1 * s2; vr = -c1 * s1; ui =  s1 * c2; vi = c1 * c1; }
    if (j == P - 1) {
        float ps = psi[k];
        float cp = cosf(ps), sp = sinf(ps);
        float ur2 = cp * ur - sp * ui, ui2 = sp * ur + cp * ui;
        float vr2 = cp * vr - sp * vi, vi2 = sp * vr + cp * vi;
        ur = ur2; ui = ui2; vr = vr2; vi = vi2;
    }
    coef[idx] = make_float4(ur, ui, vr, vi);
}

// ---------------------------------------------------------------------------
// Intra-thread butterfly stage over R rows: partner differs in bit PM of e.
// One coef pair load serves all R rows (R independent chains = ILP).
// ---------------------------------------------------------------------------
template <int J, int PM>
__device__ __forceinline__ void stage_intra(float (&re)[R][16], float (&im)[R][16],
                                            const float4* __restrict__ coef, int lane) {
    const float4* cj = coef + J * D + lane;
#pragma unroll
    for (int e0 = 0; e0 < 16; ++e0) {
        if (e0 & PM) continue;
        const int e1 = e0 | PM;
        float4 c0 = cj[e0 * 64];
        float4 c1 = cj[e1 * 64];
#pragma unroll
        for (int r = 0; r < R; ++r) {
            float ar0 = re[r][e0], ai0 = im[r][e0], ar1 = re[r][e1], ai1 = im[r][e1];
            re[r][e0] = c0.x * ar0 - c0.y * ai0 + c0.z * ar1 - c0.w * ai1;
            im[r][e0] = c0.x * ai0 + c0.y * ar0 + c0.z * ai1 + c0.w * ar1;
            re[r][e1] = c1.x * ar1 - c1.y * ai1 + c1.z * ar0 - c1.w * ai0;
            im[r][e1] = c1.x * ai1 + c1.y * ar1 + c1.z * ai0 + c1.w * ar0;
        }
    }
}

// ---------------------------------------------------------------------------
// Cross-lane butterfly stage over R rows: partner differs in lane bit (J-2).
// ---------------------------------------------------------------------------
template <int J>
__device__ __forceinline__ void stage_shfl(float (&re)[R][16], float (&im)[R][16],
                                           const float4* __restrict__ coef, int lane) {
    const int mask = 1 << (J - 2);
    const float4* cj = coef + J * D + lane;
#pragma unroll
    for (int e = 0; e < 16; ++e) {
        float4 c = cj[e * 64];
#pragma unroll
        for (int r = 0; r < R; ++r) {
            float sre = __shfl_xor(re[r][e], mask);
            float sim = __shfl_xor(im[r][e], mask);
            float nre = c.x * re[r][e] - c.y * im[r][e] + c.z * sre - c.w * sim;
            float nim = c.x * im[r][e] + c.y * re[r][e] + c.z * sim + c.w * sre;
            re[r][e] = nre; im[r][e] = nim;
        }
    }
}

__global__ __launch_bounds__(256) void fft_kernel(const float* __restrict__ X,
                                                  const float4* __restrict__ coef,
                                                  float* __restrict__ out) {
    const int lane = threadIdx.x & 63;
    const int wave = threadIdx.x >> 6;
    const long rowbase = ((long)blockIdx.x * 4 + wave) * R;
    const float* xb = X + rowbase * 2048 + lane * 4;

    float re[R][16], im[R][16];
#pragma unroll
    for (int r = 0; r < R; ++r) {
        if (rowbase + r < NROWS) {             // wave-uniform guard
            const float* xr = xb + r * 2048;
#pragma unroll
            for (int eh = 0; eh < 4; ++eh) {
                float4 vr = *(const float4*)(xr + eh * 256);
                float4 vi = *(const float4*)(xr + 1024 + eh * 256);
                re[r][eh * 4 + 0] = vr.x; re[r][eh * 4 + 1] = vr.y;
                re[r][eh * 4 + 2] = vr.z; re[r][eh * 4 + 3] = vr.w;
                im[r][eh * 4 + 0] = vi.x; im[r][eh * 4 + 1] = vi.y;
                im[r][eh * 4 + 2] = vi.z; im[r][eh * 4 + 3] = vi.w;
            }
        } else {
#pragma unroll
            for (int e = 0; e < 16; ++e) { re[r][e] = 0.f; im[r][e] = 0.f; }
        }
    }

    stage_intra<0, 1>(re, im, coef, lane);
    stage_intra<1, 2>(re, im, coef, lane);

    stage_shfl<2>(re, im, coef, lane);
    stage_shfl<3>(re, im, coef, lane);
    stage_shfl<4>(re, im, coef, lane);
    stage_shfl<5>(re, im, coef, lane);
    stage_shfl<6>(re, im, coef, lane);
    stage_shfl<7>(re, im, coef, lane);

    stage_intra<8, 4>(re, im, coef, lane);
    stage_intra<9, 8>(re, im, coef, lane);

    float* ob = out + rowbase * 2048 + lane * 4;
#pragma unroll
    for (int r = 0; r < R; ++r) {
        if (rowbase + r < NROWS) {             // wave-uniform guard
            float* orow = ob + r * 2048;
#pragma unroll
            for (int eh = 0; eh < 4; ++eh) {
                nfloat4 vr = { re[r][eh * 4 + 0], re[r][eh * 4 + 1], re[r][eh * 4 + 2], re[r][eh * 4 + 3] };
                nfloat4 vi = { im[r][eh * 4 + 0], im[r][eh * 4 + 1], im[r][eh * 4 + 2], im[r][eh * 4 + 3] };
                __builtin_nontemporal_store(vr, (nfloat4*)(orow + eh * 256));
                __builtin_nontemporal_store(vi, (nfloat4*)(orow + 1024 + eh * 256));
            }
        }
    }
}

extern "C" void kernel_launch(void* const* d_in, const int* in_sizes, int n_in,
                              void* d_out, int out_size, void* d_ws, size_t ws_size,
                              hipStream_t stream) {
    const float* X     = (const float*)d_in[0];
    const float* theta = (const float*)d_in[1];
    const float* phi   = (const float*)d_in[2];
    const float* psi   = (const float*)d_in[3];
    float4* coef = (float4*)d_ws;   // P*D*sizeof(float4) = 160 KB

    coef_kernel<<<(P * D + 255) / 256, 256, 0, stream>>>(theta, phi, psi, coef);
    const int rows_per_block = 4 * R;          // 4 waves x R rows
    const int grid = (NROWS + rows_per_block - 1) / rows_per_block;
    fft_kernel<<<grid, 256, 0, stream>>>(X, coef, (float*)d_out);
}

// Round 9
// 139.594 us; speedup vs baseline: 1.0067x; 1.0067x over previous
//
#include <hip/hip_runtime.h>

#define P 10
#define D 1024
#define NROWS 16384

typedef float nfloat4 __attribute__((ext_vector_type(4)));   // clang-native for nontemporal builtins

// ---------------------------------------------------------------------------
// Column mapping (r4 keeper):
//   k = e_hi*256 + lane*4 + e_lo,  e = e_hi*4 + e_lo,  e in [0,16), lane in [0,64)
//   stage j flips bit j of k:
//     j=0,1 -> e bits 0,1 (intra) | j=2..7 -> lane bit j-2 (shfl) | j=8,9 -> e bits 2,3 (intra)
//
// NEW: pair-compressed coef table. For a butterfly pair, all four complex
// coefs derive from base (s1,c1,s2,c2):
//   A=(-s2,c2), B=(-s1,c1);  u0=s1*A, v0=c1*B, u1=-s1*B, v1=c1*A
// ctab[j*512 + slot] = (s1,c1,s2,c2) of the pair, slot =
//   intra j (0,1,8):  pidx(e0)*64 + lane       (one load per pair)
//   shfl  j (2..7):   e*32 + lanec             (partner lanes share address)
// Stage 9 keeps per-column (u,v) with psi folded: c9[e*64+lane] at ctab+5120.
// ---------------------------------------------------------------------------
__global__ void coef_kernel(const float* __restrict__ theta,
                            const float* __restrict__ phi,
                            const float* __restrict__ psi,
                            float4* __restrict__ ctab) {
    int idx = blockIdx.x * blockDim.x + threadIdx.x;
    if (idx >= 9 * 512 + 1024) return;
    if (idx < 9 * 512) {                        // compressed stages 0..8
        int j = idx >> 9;
        int slot = idx & 511;
        int k0;
        if (j < 2 || j == 8) {                  // intra: slot = pidx*64 + lane
            int PM = (j == 0) ? 1 : (j == 1) ? 2 : 4;
            int pidx = slot >> 6, lane = slot & 63;
            int e0 = (pidx & (PM - 1)) | ((pidx & ~(PM - 1)) << 1);
            k0 = ((e0 >> 2) << 8) | (lane << 2) | (e0 & 3);
        } else {                                // shfl: slot = e*32 + lanec
            int mask = 1 << (j - 2);
            int e = slot >> 5, lanec = slot & 31;
            int lane0 = (lanec & (mask - 1)) | ((lanec & ~(mask - 1)) << 1);
            k0 = ((e >> 2) << 8) | (lane0 << 2) | (e & 3);
        }
        unsigned lowmask = (1u << j) - 1u;
        unsigned m = ((unsigned)k0 & lowmask) | (((unsigned)k0 >> 1) & ~lowmask);
        float th = theta[j * (D / 2) + m];
        float ph = phi[j * (D / 2) + m];
        float h = th * 0.5f;
        ctab[idx] = make_float4(sinf(h), cosf(h), sinf(h + ph), cosf(h + ph));
    } else {                                    // stage 9, old per-column format
        int s = idx - 9 * 512;
        int e = s >> 6, lane = s & 63;
        int k = ((e >> 2) << 8) | (lane << 2) | (e & 3);
        int b = (k >> 9) & 1;
        unsigned m = (unsigned)k & 511u;        // delete top bit
        float th = theta[9 * (D / 2) + m];
        float ph = phi[9 * (D / 2) + m];
        float h = th * 0.5f;
        float s1 = sinf(h), c1 = cosf(h);
        float s2 = sinf(h + ph), c2 = cosf(h + ph);
        float ur, ui, vr, vi;
        if (b) { ur =  s1 * s1; vr = -c1 * s2; ui = -c1 * s1; vi = c1 * c2; }
        else   { ur = -s1 * s2; vr = -c1 * s1; ui =  s1 * c2; vi = c1 * c1; }
        float ps = psi[k];
        float cp = cosf(ps), sp = sinf(ps);
        float ur2 = cp * ur - sp * ui, ui2 = sp * ur + cp * ui;
        float vr2 = cp * vr - sp * vi, vi2 = sp * vr + cp * vi;
        ctab[5120 + s] = make_float4(ur2, ui2, vr2, vi2);
    }
}

// ---------------------------------------------------------------------------
// Compressed intra stage (j=0,1,8): one base load per pair; P/Q algebra.
//   Pr' = s2*x0r + c2*x0i (= -Re(A x0)),  Pi = c2*x0r - s2*x0i
//   Qr' = s1*x1r + c1*x1i (= -Re(B x1)),  Qi = c1*x1r - s1*x1i
//   y0 = (-(s1 Pr' + c1 Qr'),  s1 Pi + c1 Qi)
//   y1 = ( s1 Qr' - c1 Pr',    c1 Pi - s1 Qi)
// ---------------------------------------------------------------------------
template <int J, int PM>
__device__ __forceinline__ void stage_intra_c(float (&ra)[16], float (&ia)[16],
                                              float (&rb)[16], float (&ib)[16],
                                              const float4* __restrict__ ctab, int lane) {
    const float4* cj = ctab + J * 512 + lane;
#pragma unroll
    for (int e0 = 0; e0 < 16; ++e0) {
        if (e0 & PM) continue;
        const int e1 = e0 | PM;
        const int pidx = (e0 & (PM - 1)) | ((e0 >> 1) & ~(PM - 1));
        float4 c = cj[pidx * 64];
        float s1 = c.x, c1 = c.y, s2 = c.z, c2 = c.w;
        {
            float Pr = s2 * ra[e0] + c2 * ia[e0];
            float Pi = c2 * ra[e0] - s2 * ia[e0];
            float Qr = s1 * ra[e1] + c1 * ia[e1];
            float Qi = c1 * ra[e1] - s1 * ia[e1];
            ra[e0] = -(s1 * Pr + c1 * Qr);
            ia[e0] =   s1 * Pi + c1 * Qi;
            ra[e1] =   s1 * Qr - c1 * Pr;
            ia[e1] =   c1 * Pi - s1 * Qi;
        }
        {
            float Pr = s2 * rb[e0] + c2 * ib[e0];
            float Pi = c2 * rb[e0] - s2 * ib[e0];
            float Qr = s1 * rb[e1] + c1 * ib[e1];
            float Qi = c1 * rb[e1] - s1 * ib[e1];
            rb[e0] = -(s1 * Pr + c1 * Qr);
            ib[e0] =   s1 * Pi + c1 * Qi;
            rb[e1] =   s1 * Qr - c1 * Pr;
            ib[e1] =   c1 * Pi - s1 * Qi;
        }
    }
}

// ---------------------------------------------------------------------------
// Compressed cross-lane stage (j=2..7): partner lanes load the SAME base
// address (half TCP bytes); per-lane u,v rebuilt in ~10 VALU ops shared
// across both rows, then the original 8-FMA butterfly per row.
//   b=0: u=(-s1*s2, s1*c2) v=(-c1*s1, c1*c1)
//   b=1: u=( s1*s1,-c1*s1) v=(-c1*s2, c1*c2)
// ---------------------------------------------------------------------------
template <int J>
__device__ __forceinline__ void stage_shfl_c(float (&ra)[16], float (&ia)[16],
                                             float (&rb)[16], float (&ib)[16],
                                             const float4* __restrict__ ctab, int lane) {
    const int mask = 1 << (J - 2);
    const int lanec = (lane & (mask - 1)) | ((lane >> 1) & ~(mask - 1));
    const bool bs = (lane & mask) != 0;
    const float4* cj = ctab + J * 512 + lanec;
#pragma unroll
    for (int e = 0; e < 16; ++e) {
        float4 c = cj[e * 32];
        float s1 = c.x, c1 = c.y, s2 = c.z, c2 = c.w;
        float ur =  s1 * (bs ?  s1 : -s2);
        float ui =  s1 * (bs ? -c1 :  c2);
        float vr = -c1 * (bs ?  s2 :  s1);
        float vi =  c1 * (bs ?  c2 :  c1);
        float sra = __shfl_xor(ra[e], mask);
        float sia = __shfl_xor(ia[e], mask);
        float srb = __shfl_xor(rb[e], mask);
        float sib = __shfl_xor(ib[e], mask);
        float nra = ur * ra[e] - ui * ia[e] + vr * sra - vi * sia;
        float nia = ur * ia[e] + ui * ra[e] + vr * sia + vi * sra;
        float nrb = ur * rb[e] - ui * ib[e] + vr * srb - vi * sib;
        float nib = ur * ib[e] + ui * rb[e] + vr * sib + vi * srb;
        ra[e] = nra; ia[e] = nia; rb[e] = nrb; ib[e] = nib;
    }
}

// ---------------------------------------------------------------------------
// Stage 9: old per-column coef4 (psi folded), PM=8 intra butterfly.
// ---------------------------------------------------------------------------
__device__ __forceinline__ void stage9(float (&ra)[16], float (&ia)[16],
                                       float (&rb)[16], float (&ib)[16],
                                       const float4* __restrict__ c9, int lane) {
    const float4* cj = c9 + lane;
#pragma unroll
    for (int e0 = 0; e0 < 8; ++e0) {
        const int e1 = e0 | 8;
        float4 c0 = cj[e0 * 64];
        float4 c1 = cj[e1 * 64];
        float ar0 = ra[e0], ai0 = ia[e0], ar1 = ra[e1], ai1 = ia[e1];
        float br0 = rb[e0], bi0 = ib[e0], br1 = rb[e1], bi1 = ib[e1];
        ra[e0] = c0.x * ar0 - c0.y * ai0 + c0.z * ar1 - c0.w * ai1;
        ia[e0] = c0.x * ai0 + c0.y * ar0 + c0.z * ai1 + c0.w * ar1;
        ra[e1] = c1.x * ar1 - c1.y * ai1 + c1.z * ar0 - c1.w * ai0;
        ia[e1] = c1.x * ai1 + c1.y * ar1 + c1.z * ai0 + c1.w * ar0;
        rb[e0] = c0.x * br0 - c0.y * bi0 + c0.z * br1 - c0.w * bi1;
        ib[e0] = c0.x * bi0 + c0.y * br0 + c0.z * bi1 + c0.w * br1;
        rb[e1] = c1.x * br1 - c1.y * bi1 + c1.z * br0 - c1.w * bi0;
        ib[e1] = c1.x * bi1 + c1.y * br1 + c1.z * bi0 + c1.w * br0;
    }
}

__global__ __launch_bounds__(256) void fft_kernel(const float* __restrict__ X,
                                                  const float4* __restrict__ ctab,
                                                  float* __restrict__ out) {
    const int lane = threadIdx.x & 63;
    const int wave = threadIdx.x >> 6;
    const long rowbase = (long)blockIdx.x * 8 + (long)wave * 2;
    const float* x0 = X + rowbase * 2048 + lane * 4;
    const float* x1 = x0 + 2048;

    float ra[16], ia[16], rb[16], ib[16];
#pragma unroll
    for (int eh = 0; eh < 4; ++eh) {
        float4 v0r = *(const float4*)(x0 + eh * 256);
        float4 v0i = *(const float4*)(x0 + 1024 + eh * 256);
        float4 v1r = *(const float4*)(x1 + eh * 256);
        float4 v1i = *(const float4*)(x1 + 1024 + eh * 256);
        ra[eh * 4 + 0] = v0r.x; ra[eh * 4 + 1] = v0r.y; ra[eh * 4 + 2] = v0r.z; ra[eh * 4 + 3] = v0r.w;
        ia[eh * 4 + 0] = v0i.x; ia[eh * 4 + 1] = v0i.y; ia[eh * 4 + 2] = v0i.z; ia[eh * 4 + 3] = v0i.w;
        rb[eh * 4 + 0] = v1r.x; rb[eh * 4 + 1] = v1r.y; rb[eh * 4 + 2] = v1r.z; rb[eh * 4 + 3] = v1r.w;
        ib[eh * 4 + 0] = v1i.x; ib[eh * 4 + 1] = v1i.y; ib[eh * 4 + 2] = v1i.z; ib[eh * 4 + 3] = v1i.w;
    }

    stage_intra_c<0, 1>(ra, ia, rb, ib, ctab, lane);
    stage_intra_c<1, 2>(ra, ia, rb, ib, ctab, lane);

    stage_shfl_c<2>(ra, ia, rb, ib, ctab, lane);
    stage_shfl_c<3>(ra, ia, rb, ib, ctab, lane);
    stage_shfl_c<4>(ra, ia, rb, ib, ctab, lane);
    stage_shfl_c<5>(ra, ia, rb, ib, ctab, lane);
    stage_shfl_c<6>(ra, ia, rb, ib, ctab, lane);
    stage_shfl_c<7>(ra, ia, rb, ib, ctab, lane);

    stage_intra_c<8, 4>(ra, ia, rb, ib, ctab, lane);
    stage9(ra, ia, rb, ib, ctab + 5120, lane);

    float* o0 = out + rowbase * 2048 + lane * 4;
    float* o1 = o0 + 2048;
#pragma unroll
    for (int eh = 0; eh < 4; ++eh) {
        nfloat4 v0r = { ra[eh * 4 + 0], ra[eh * 4 + 1], ra[eh * 4 + 2], ra[eh * 4 + 3] };
        nfloat4 v0i = { ia[eh * 4 + 0], ia[eh * 4 + 1], ia[eh * 4 + 2], ia[eh * 4 + 3] };
        nfloat4 v1r = { rb[eh * 4 + 0], rb[eh * 4 + 1], rb[eh * 4 + 2], rb[eh * 4 + 3] };
        nfloat4 v1i = { ib[eh * 4 + 0], ib[eh * 4 + 1], ib[eh * 4 + 2], ib[eh * 4 + 3] };
        __builtin_nontemporal_store(v0r, (nfloat4*)(o0 + eh * 256));
        __builtin_nontemporal_store(v0i, (nfloat4*)(o0 + 1024 + eh * 256));
        __builtin_nontemporal_store(v1r, (nfloat4*)(o1 + eh * 256));
        __builtin_nontemporal_store(v1i, (nfloat4*)(o1 + 1024 + eh * 256));
    }
}

extern "C" void kernel_launch(void* const* d_in, const int* in_sizes, int n_in,
                              void* d_out, int out_size, void* d_ws, size_t ws_size,
                              hipStream_t stream) {
    const float* X     = (const float*)d_in[0];
    const float* theta = (const float*)d_in[1];
    const float* phi   = (const float*)d_in[2];
    const float* psi   = (const float*)d_in[3];
    float4* ctab = (float4*)d_ws;   // 5120 compressed + 1024 stage-9 = 96 KB

    coef_kernel<<<(9 * 512 + 1024 + 255) / 256, 256, 0, stream>>>(theta, phi, psi, ctab);
    fft_kernel<<<NROWS / 8, 256, 0, stream>>>(X, ctab, (float*)d_out);
}

// Round 10
// 74.584 us; speedup vs baseline: 1.8843x; 1.8716x over previous
//
#include <hip/hip_runtime.h>
#include <hip/hip_fp16.h>

#define P 10
#define D 1024
#define NROWS 16384

typedef float nfloat4 __attribute__((ext_vector_type(4)));   // clang-native for nontemporal builtins

// ---------------------------------------------------------------------------
// Column mapping (r4 keeper):
//   k = e_hi*256 + lane*4 + e_lo,  e = e_hi*4 + e_lo,  e in [0,16), lane in [0,64)
//   stage j flips bit j of k:
//     j=0,1 -> e bits 0,1 (intra) | j=2..7 -> lane bit j-2 (shfl) | j=8,9 -> e bits 2,3 (intra)
// Coef table swizzled: ctab[j*D + e*64 + lane] = coefs for column k(e,lane).
// psi folded into stage-9 coefs.
//
// THIS ROUND (only change vs r4): coef entries stored as 4 x f16 (8 B, uint2)
// instead of 4 x f32 (16 B). Butterfly math stays f32 via __half2float --
// the a*b+c shapes match v_fma_mix_f32, so f32 precision from f16 operands.
// Halves the per-wave coefficient TCP bytes (160 KB -> 80 KB per wave).
// ---------------------------------------------------------------------------
__global__ void coef_kernel(const float* __restrict__ theta,
                            const float* __restrict__ phi,
                            const float* __restrict__ psi,
                            uint2* __restrict__ ctab) {
    int idx = blockIdx.x * blockDim.x + threadIdx.x;
    if (idx >= P * D) return;
    int j = idx >> 10;
    int slot = idx & (D - 1);
    int e = slot >> 6;
    int lane = slot & 63;
    int k = ((e >> 2) << 8) + (lane << 2) + (e & 3);   // column this slot serves
    int b = (k >> j) & 1;
    unsigned lowmask = (1u << j) - 1u;
    unsigned m = ((unsigned)k & lowmask) | (((unsigned)k >> 1) & ~lowmask); // delete bit j
    float th = theta[j * (D / 2) + m];
    float ph = phi[j * (D / 2) + m];
    float h = th * 0.5f;
    float s1 = sinf(h), c1 = cosf(h);
    float s2 = sinf(h + ph), c2 = cosf(h + ph);
    float ur, ui, vr, vi;
    if (b) { ur =  s1 * s1; vr = -c1 * s2; ui = -c1 * s1; vi = c1 * c2; }
    else   { ur = -s1 * s2; vr = -c1 * s1; ui =  s1 * c2; vi = c1 * c1; }
    if (j == P - 1) {
        float ps = psi[k];
        float cp = cosf(ps), sp = sinf(ps);
        float ur2 = cp * ur - sp * ui, ui2 = sp * ur + cp * ui;
        float vr2 = cp * vr - sp * vi, vi2 = sp * vr + cp * vi;
        ur = ur2; ui = ui2; vr = vr2; vi = vi2;
    }
    __half2 uh = __floats2half2_rn(ur, ui);
    __half2 vh = __floats2half2_rn(vr, vi);
    uint2 w;
    w.x = *reinterpret_cast<unsigned int*>(&uh);
    w.y = *reinterpret_cast<unsigned int*>(&vh);
    ctab[idx] = w;
}

__device__ __forceinline__ void unpack_c(uint2 w, float& ur, float& ui,
                                         float& vr, float& vi) {
    __half2 a = *reinterpret_cast<__half2*>(&w.x);
    __half2 b = *reinterpret_cast<__half2*>(&w.y);
    ur = __low2float(a); ui = __high2float(a);
    vr = __low2float(b); vi = __high2float(b);
}

// ---------------------------------------------------------------------------
// Intra-thread butterfly stage: partner differs in a bit of e (mask PM).
// Identical structure to r4; only the coef load is 8 B + unpack.
// ---------------------------------------------------------------------------
template <int PM>
__device__ __forceinline__ void stage_intra(float (&ra)[16], float (&ia)[16],
                                            float (&rb)[16], float (&ib)[16],
                                            const uint2* cj) {
#pragma unroll
    for (int e0 = 0; e0 < 16; ++e0) {
        if (e0 & PM) continue;
        const int e1 = e0 | PM;
        uint2 w0 = cj[e0 * 64];
        uint2 w1 = cj[e1 * 64];
        float u0r, u0i, v0r, v0i, u1r, u1i, v1r, v1i;
        unpack_c(w0, u0r, u0i, v0r, v0i);
        unpack_c(w1, u1r, u1i, v1r, v1i);
        float ar0 = ra[e0], ai0 = ia[e0], ar1 = ra[e1], ai1 = ia[e1];
        float br0 = rb[e0], bi0 = ib[e0], br1 = rb[e1], bi1 = ib[e1];
        ra[e0] = u0r * ar0 - u0i * ai0 + v0r * ar1 - v0i * ai1;
        ia[e0] = u0r * ai0 + u0i * ar0 + v0r * ai1 + v0i * ar1;
        ra[e1] = u1r * ar1 - u1i * ai1 + v1r * ar0 - v1i * ai0;
        ia[e1] = u1r * ai1 + u1i * ar1 + v1r * ai0 + v1i * ar0;
        rb[e0] = u0r * br0 - u0i * bi0 + v0r * br1 - v0i * bi1;
        ib[e0] = u0r * bi0 + u0i * br0 + v0r * bi1 + v0i * br1;
        rb[e1] = u1r * br1 - u1i * bi1 + v1r * br0 - v1i * bi0;
        ib[e1] = u1r * bi1 + u1i * br1 + v1r * bi0 + v1i * br0;
    }
}

// ---------------------------------------------------------------------------
// Cross-lane butterfly stage: partner differs in lane bit; MASK = xor mask.
// ---------------------------------------------------------------------------
template <int MASK>
__device__ __forceinline__ void stage_shfl(float (&ra)[16], float (&ia)[16],
                                           float (&rb)[16], float (&ib)[16],
                                           const uint2* cj) {
#pragma unroll
    for (int e = 0; e < 16; ++e) {
        uint2 w = cj[e * 64];
        float ur, ui, vr, vi;
        unpack_c(w, ur, ui, vr, vi);
        float sra = __shfl_xor(ra[e], MASK);
        float sia = __shfl_xor(ia[e], MASK);
        float srb = __shfl_xor(rb[e], MASK);
        float sib = __shfl_xor(ib[e], MASK);
        float nra = ur * ra[e] - ui * ia[e] + vr * sra - vi * sia;
        float nia = ur * ia[e] + ui * ra[e] + vr * sia + vi * sra;
        float nrb = ur * rb[e] - ui * ib[e] + vr * srb - vi * sib;
        float nib = ur * ib[e] + ui * rb[e] + vr * sib + vi * srb;
        ra[e] = nra; ia[e] = nia; rb[e] = nrb; ib[e] = nib;
    }
}

__global__ __launch_bounds__(256) void fft_kernel(const float* __restrict__ X,
                                                  const uint2* __restrict__ ctab,
                                                  float* __restrict__ out) {
    const int lane = threadIdx.x & 63;
    const int wave = threadIdx.x >> 6;
    const long rowbase = (long)blockIdx.x * 8 + (long)wave * 2;
    const float* x0 = X + rowbase * 2048 + lane * 4;
    const float* x1 = x0 + 2048;
    const uint2* cb = ctab + lane;

    float ra[16], ia[16], rb[16], ib[16];
#pragma unroll
    for (int eh = 0; eh < 4; ++eh) {
        float4 v0r = *(const float4*)(x0 + eh * 256);
        float4 v0i = *(const float4*)(x0 + 1024 + eh * 256);
        float4 v1r = *(const float4*)(x1 + eh * 256);
        float4 v1i = *(const float4*)(x1 + 1024 + eh * 256);
        ra[eh * 4 + 0] = v0r.x; ra[eh * 4 + 1] = v0r.y; ra[eh * 4 + 2] = v0r.z; ra[eh * 4 + 3] = v0r.w;
        ia[eh * 4 + 0] = v0i.x; ia[eh * 4 + 1] = v0i.y; ia[eh * 4 + 2] = v0i.z; ia[eh * 4 + 3] = v0i.w;
        rb[eh * 4 + 0] = v1r.x; rb[eh * 4 + 1] = v1r.y; rb[eh * 4 + 2] = v1r.z; rb[eh * 4 + 3] = v1r.w;
        ib[eh * 4 + 0] = v1i.x; ib[eh * 4 + 1] = v1i.y; ib[eh * 4 + 2] = v1i.z; ib[eh * 4 + 3] = v1i.w;
    }

    stage_intra<1>(ra, ia, rb, ib, cb + 0 * D);
    stage_intra<2>(ra, ia, rb, ib, cb + 1 * D);

    stage_shfl<1>(ra, ia, rb, ib, cb + 2 * D);
    stage_shfl<2>(ra, ia, rb, ib, cb + 3 * D);
    stage_shfl<4>(ra, ia, rb, ib, cb + 4 * D);
    stage_shfl<8>(ra, ia, rb, ib, cb + 5 * D);
    stage_shfl<16>(ra, ia, rb, ib, cb + 6 * D);
    stage_shfl<32>(ra, ia, rb, ib, cb + 7 * D);

    stage_intra<4>(ra, ia, rb, ib, cb + 8 * D);
    stage_intra<8>(ra, ia, rb, ib, cb + 9 * D);

    float* o0 = out + rowbase * 2048 + lane * 4;
    float* o1 = o0 + 2048;
#pragma unroll
    for (int eh = 0; eh < 4; ++eh) {
        nfloat4 v0r = { ra[eh * 4 + 0], ra[eh * 4 + 1], ra[eh * 4 + 2], ra[eh * 4 + 3] };
        nfloat4 v0i = { ia[eh * 4 + 0], ia[eh * 4 + 1], ia[eh * 4 + 2], ia[eh * 4 + 3] };
        nfloat4 v1r = { rb[eh * 4 + 0], rb[eh * 4 + 1], rb[eh * 4 + 2], rb[eh * 4 + 3] };
        nfloat4 v1i = { ib[eh * 4 + 0], ib[eh * 4 + 1], ib[eh * 4 + 2], ib[eh * 4 + 3] };
        __builtin_nontemporal_store(v0r, (nfloat4*)(o0 + eh * 256));
        __builtin_nontemporal_store(v0i, (nfloat4*)(o0 + 1024 + eh * 256));
        __builtin_nontemporal_store(v1r, (nfloat4*)(o1 + eh * 256));
        __builtin_nontemporal_store(v1i, (nfloat4*)(o1 + 1024 + eh * 256));
    }
}

extern "C" void kernel_launch(void* const* d_in, const int* in_sizes, int n_in,
                              void* d_out, int out_size, void* d_ws, size_t ws_size,
                              hipStream_t stream) {
    const float* X     = (const float*)d_in[0];
    const float* theta = (const float*)d_in[1];
    const float* phi   = (const float*)d_in[2];
    const float* psi   = (const float*)d_in[3];
    uint2* ctab = (uint2*)d_ws;   // P*D*8 B = 80 KB

    coef_kernel<<<(P * D + 255) / 256, 256, 0, stream>>>(theta, phi, psi, ctab);
    fft_kernel<<<NROWS / 8, 256, 0, stream>>>(X, ctab, (float*)d_out);
}